// Round 11
// baseline (229.278 us; speedup 1.0000x reference)
//
#include <hip/hip_runtime.h>
#include <hip/hip_bf16.h>

// ---------------------------------------------------------------------------
// ChebConv encoder: 2x ChebConv(K=3), sym norm, lambda_max=2 => L_hat = -D^-1/2 A D^-1/2
// N=30000, IN=128, HID=256, E=480000
//
// Round 11: channel-split laps. Each lap runs as grid (N/8, 2): y = channel
// half (64 ch = 128B half-rows). Gather working set per half = 3.84MB -> fits
// a 4MiB per-XCD L2 (full rows were 7.7MB -> ~50% miss). Wave = 2 nodes x 32
// lanes. Exact-tail unroll x4 (round-10's padded unroll x8 added 25% gather
// waste -> reverted). Build/prep/GEMM unchanged from round 10.
//   layer1: T1b = L xb ; T2b = 2 L T1b - xb ; hb = relu([xb|T1b|T2b]@W1cat + b1)
//   layer2: [Db|A2b|Zb] = hb @ [W1'|W2'|W0'-W2'] ; Ib = 2 L A2b + Db ;
//           out = L Ib + Zb + b2
// ---------------------------------------------------------------------------

#define ELLW 64

typedef short bf16x8_t __attribute__((ext_vector_type(8)));
typedef unsigned short u16x4_t __attribute__((ext_vector_type(4)));
typedef unsigned short u16x8_t __attribute__((ext_vector_type(8)));
typedef float f32x4_t __attribute__((ext_vector_type(4)));

static __device__ inline unsigned short f2bf(float f) {
    __hip_bfloat16 h = __float2bfloat16(f);
    return __builtin_bit_cast(unsigned short, h);
}
static __device__ inline float bfbits2f(unsigned int lo16) {
    unsigned int u = lo16 << 16;
    return __builtin_bit_cast(float, u);
}

// ---------------- ELL build: degi[s]++ (masked), ell[d*64 + cnt[d]++] = s ----
__global__ __launch_bounds__(256) void build_kernel(const int* __restrict__ src,
                                                    const int* __restrict__ dst,
                                                    int* __restrict__ degi,
                                                    int* __restrict__ cnt,
                                                    unsigned short* __restrict__ ell,
                                                    int E) {
    int e = blockIdx.x * 256 + threadIdx.x;
    if (e >= E) return;
    int s = src[e], d = dst[e];
    if (s != d) atomicAdd(&degi[s], 1);
    int pos = atomicAdd(&cnt[d], 1);
    if (pos < ELLW) ell[(size_t)d * ELLW + pos] = (unsigned short)s;
}

// ---------------- fused prep: Bt1, Bt2, x->bf16 ----------------
__global__ __launch_bounds__(256) void prep_kernel(const float* __restrict__ W1,
                                                   const float* __restrict__ W2,
                                                   const float* __restrict__ x,
                                                   unsigned short* __restrict__ Bt1,
                                                   unsigned short* __restrict__ Bt2,
                                                   unsigned short* __restrict__ xb,
                                                   int nx4) {
    const int NB1 = 256 * 384, NB2 = 384 * 256;
    int i = blockIdx.x * 256 + threadIdx.x;
    if (i < NB1) {
        int n = i / 384, k = i % 384;
        Bt1[(size_t)n * 384 + k] = f2bf(W1[(size_t)k * 256 + n]);
    } else if (i < NB1 + NB2) {
        int j = i - NB1;
        int n = j / 256, k = j % 256;
        float v;
        if (n < 128) v = W2[(size_t)(1 * 256 + k) * 128 + n];
        else if (n < 256) v = W2[(size_t)(2 * 256 + k) * 128 + (n - 128)];
        else v = W2[(size_t)k * 128 + (n - 256)] - W2[(size_t)(2 * 256 + k) * 128 + (n - 256)];
        Bt2[(size_t)n * 256 + k] = f2bf(v);
    } else {
        int j = i - NB1 - NB2;
        if (j < nx4) {
            f32x4_t v = *(const f32x4_t*)&x[(size_t)j * 4];
            u16x4_t u;
            u.x = f2bf(v.x); u.y = f2bf(v.y); u.z = f2bf(v.z); u.w = f2bf(v.w);
            *(u16x4_t*)&xb[(size_t)j * 4] = u;
        }
    }
}

// ---------------- ELL lap, bf16 gather, channel-split ----------------
// grid (ceil(N/8), 2): y = channel half. Wave = 2 nodes x 32 lanes; each
// half-wave gathers 128B half-rows Xb[sk*128 + half*64 .. +64).
// res = s * sum_e w_e * Xb[ell_e, cols] + a*add[node, cols] + bias[cols]
// w_e = -rsqrt(deg[node]*deg[src_e]), 0 on self-loop/zero-degree.
__global__ __launch_bounds__(256) void lap_ell_kernel(const unsigned short* __restrict__ Xb,
                                                      float* __restrict__ Yf,
                                                      unsigned short* __restrict__ Yb,
                                                      const int* __restrict__ cnt,
                                                      const unsigned short* __restrict__ ell,
                                                      const int* __restrict__ degi,
                                                      const unsigned short* __restrict__ add,
                                                      const float* __restrict__ bias,
                                                      float s, float a, int N) {
    int tid = threadIdx.x;
    int wave = tid >> 6;
    int lane = tid & 63;
    int sub = lane >> 5;           // node within wave
    int l32 = lane & 31;
    int node = blockIdx.x * 8 + wave * 2 + sub;
    if (node >= N) return;
    int col = blockIdx.y * 64 + l32 * 2;   // 2 channels per lane

    int n = cnt[node];
    if (n > ELLW) n = ELLW;
    int dn = degi[node];
    float fdn = (float)dn;
    const unsigned short* row = ell + (size_t)node * ELLW;
    const unsigned short* Xc = Xb + col;

    float ax0 = 0.f, ay0 = 0.f, ax1 = 0.f, ay1 = 0.f;
    float ax2 = 0.f, ay2 = 0.f, ax3 = 0.f, ay3 = 0.f;
    int j = 0;
    for (; j + 4 <= n; j += 4) {
        u16x4_t s4 = *(const u16x4_t*)&row[j];
        int s0 = (int)s4.x, s1 = (int)s4.y, s2 = (int)s4.z, s3 = (int)s4.w;
        unsigned int v0 = *(const unsigned int*)&Xc[(size_t)s0 * 128];
        unsigned int v1 = *(const unsigned int*)&Xc[(size_t)s1 * 128];
        unsigned int v2 = *(const unsigned int*)&Xc[(size_t)s2 * 128];
        unsigned int v3 = *(const unsigned int*)&Xc[(size_t)s3 * 128];
        int d0 = degi[s0], d1 = degi[s1], d2 = degi[s2], d3 = degi[s3];
        float w0 = (s0 != node && dn > 0 && d0 > 0) ? -rsqrtf(fdn * (float)d0) : 0.0f;
        float w1 = (s1 != node && dn > 0 && d1 > 0) ? -rsqrtf(fdn * (float)d1) : 0.0f;
        float w2 = (s2 != node && dn > 0 && d2 > 0) ? -rsqrtf(fdn * (float)d2) : 0.0f;
        float w3 = (s3 != node && dn > 0 && d3 > 0) ? -rsqrtf(fdn * (float)d3) : 0.0f;
        ax0 = fmaf(w0, bfbits2f(v0 & 0xffffu), ax0);
        ay0 = fmaf(w0, bfbits2f(v0 >> 16), ay0);
        ax1 = fmaf(w1, bfbits2f(v1 & 0xffffu), ax1);
        ay1 = fmaf(w1, bfbits2f(v1 >> 16), ay1);
        ax2 = fmaf(w2, bfbits2f(v2 & 0xffffu), ax2);
        ay2 = fmaf(w2, bfbits2f(v2 >> 16), ay2);
        ax3 = fmaf(w3, bfbits2f(v3 & 0xffffu), ax3);
        ay3 = fmaf(w3, bfbits2f(v3 >> 16), ay3);
    }
    for (; j < n; ++j) {
        int s0 = (int)row[j];
        unsigned int v0 = *(const unsigned int*)&Xc[(size_t)s0 * 128];
        int d0 = degi[s0];
        float w0 = (s0 != node && dn > 0 && d0 > 0) ? -rsqrtf(fdn * (float)d0) : 0.0f;
        ax0 = fmaf(w0, bfbits2f(v0 & 0xffffu), ax0);
        ay0 = fmaf(w0, bfbits2f(v0 >> 16), ay0);
    }
    float rx = s * ((ax0 + ax1) + (ax2 + ax3));
    float ry = s * ((ay0 + ay1) + (ay2 + ay3));
    size_t o = (size_t)node * 128 + col;
    if (add) {
        unsigned int ad = *(const unsigned int*)&add[o];
        rx = fmaf(a, bfbits2f(ad & 0xffffu), rx);
        ry = fmaf(a, bfbits2f(ad >> 16), ry);
    }
    if (bias) {
        rx += bias[col];
        ry += bias[col + 1];
    }
    if (Yf) {
        float2 r; r.x = rx; r.y = ry;
        *(float2*)&Yf[o] = r;
    }
    if (Yb) {
        unsigned int ob = ((unsigned int)f2bf(ry) << 16) | f2bf(rx);
        *(unsigned int*)&Yb[o] = ob;
    }
}

// ---------------- bf16 MFMA GEMM, tile 128x64, 512 threads (8 waves) --------
// C[M x Ncols] = Acat[M x K](bf16 segments of 128 cols) @ Bt^T (Bt [Ncols][K] bf16)
// Output: bf16 segments of 128 cols (Ob0/Ob1/Ob2).
__global__ __launch_bounds__(512) void gemm_mfma_kernel(
        const unsigned short* __restrict__ A0, const unsigned short* __restrict__ A1,
        const unsigned short* __restrict__ A2, int ldA,
        const unsigned short* __restrict__ Bt, int K,
        unsigned short* __restrict__ Ob0, unsigned short* __restrict__ Ob1,
        unsigned short* __restrict__ Ob2,
        int ldO, const float* __restrict__ bias, int M, int relu) {
    __shared__ unsigned short As[128][72];  // [row][k], +8 pad
    __shared__ unsigned short Bs[64][72];   // [n][k]

    int tid = threadIdx.x;
    int lane = tid & 63;
    int wid = tid >> 6;          // 0..7
    int wm = wid >> 1;           // 0..3 -> 32-row band
    int wn = wid & 1;            // 0..1 -> 32-col band
    int lm = lane & 15, lg = lane >> 4;

    int rowBase = blockIdx.x * 128;
    int colBase = blockIdx.y * 64;

    f32x4_t acc[2][2] = {};

    for (int k0 = 0; k0 < K; k0 += 64) {
        int seg = k0 >> 7;
        int acol = k0 & 127;
        const unsigned short* A = (seg == 0) ? A0 : ((seg == 1) ? A1 : A2);

        // stage A: 128 rows x 64 bf16 = 16KB; 512 threads x 32B
        {
            int row = tid >> 2;            // 0..127
            int c = (tid & 3) * 16;        // 0,16,32,48
            int gr = rowBase + row;
            u16x8_t v0 = {0, 0, 0, 0, 0, 0, 0, 0};
            u16x8_t v1 = {0, 0, 0, 0, 0, 0, 0, 0};
            if (gr < M) {
                const unsigned short* ap = &A[(size_t)gr * ldA + acol + c];
                v0 = *(const u16x8_t*)ap;
                v1 = *(const u16x8_t*)(ap + 8);
            }
            *(u16x8_t*)&As[row][c] = v0;
            *(u16x8_t*)&As[row][c + 8] = v1;
        }
        // stage Bt: 64 n-rows x 64 k = 8KB; 512 threads x 16B
        {
            int n = tid >> 3;              // 0..63
            int kb = tid & 7;
            u16x8_t bv = *(const u16x8_t*)&Bt[(size_t)(colBase + n) * K + k0 + kb * 8];
            *(u16x8_t*)&Bs[n][kb * 8] = bv;
        }
        __syncthreads();

#pragma unroll
        for (int ks = 0; ks < 2; ++ks) {
            int koff = ks * 32 + lg * 8;
            bf16x8_t a0 = *(const bf16x8_t*)&As[wm * 32 + lm][koff];
            bf16x8_t a1 = *(const bf16x8_t*)&As[wm * 32 + 16 + lm][koff];
            bf16x8_t b0 = *(const bf16x8_t*)&Bs[wn * 32 + lm][koff];
            bf16x8_t b1 = *(const bf16x8_t*)&Bs[wn * 32 + 16 + lm][koff];
            acc[0][0] = __builtin_amdgcn_mfma_f32_16x16x32_bf16(a0, b0, acc[0][0], 0, 0, 0);
            acc[0][1] = __builtin_amdgcn_mfma_f32_16x16x32_bf16(a0, b1, acc[0][1], 0, 0, 0);
            acc[1][0] = __builtin_amdgcn_mfma_f32_16x16x32_bf16(a1, b0, acc[1][0], 0, 0, 0);
            acc[1][1] = __builtin_amdgcn_mfma_f32_16x16x32_bf16(a1, b1, acc[1][1], 0, 0, 0);
        }
        __syncthreads();
    }

    // epilogue: C/D layout col=lane&15, row=(lane>>4)*4+reg  [m89]
    int oseg = colBase >> 7;
    unsigned short* Ob = (oseg == 0) ? Ob0 : ((oseg == 1) ? Ob1 : Ob2);
    int lcbase = (colBase & 127) + wn * 32;
#pragma unroll
    for (int i = 0; i < 2; ++i) {
#pragma unroll
        for (int j = 0; j < 2; ++j) {
            int lc = lcbase + j * 16 + lm;
            int gcol = colBase + wn * 32 + j * 16 + lm;
            float bval = bias ? bias[gcol] : 0.0f;
#pragma unroll
            for (int r = 0; r < 4; ++r) {
                int gr = rowBase + wm * 32 + i * 16 + lg * 4 + r;
                if (gr < M) {
                    float v = acc[i][j][r] + bval;
                    if (relu) v = fmaxf(v, 0.0f);
                    Ob[(size_t)gr * ldO + lc] = f2bf(v);
                }
            }
        }
    }
}

extern "C" void kernel_launch(void* const* d_in, const int* in_sizes, int n_in,
                              void* d_out, int out_size, void* d_ws, size_t ws_size,
                              hipStream_t stream) {
    const float* x  = (const float*)d_in[0];
    const int*   ei = (const int*)d_in[1];
    const float* W1 = (const float*)d_in[2];
    const float* b1 = (const float*)d_in[3];
    const float* W2 = (const float*)d_in[4];
    const float* b2 = (const float*)d_in[5];
    float* out = (float*)d_out;

    const int IN = 128, HID = 256;
    int N = in_sizes[0] / IN;   // 30000
    int E = in_sizes[1] / 2;    // 480000
    const int* src = ei;
    const int* dst = ei + E;

    char* ws = (char*)d_ws;
    size_t off = 0;
    auto alloc = [&](size_t bytes) -> void* {
        void* p = ws + off;
        off += (bytes + 255) & ~(size_t)255;
        return p;
    };
    int* ibuf   = (int*)alloc((size_t)2 * N * 4);   // degi|cnt, one memset
    int* degi   = ibuf;
    int* cnt    = ibuf + N;
    unsigned short* ell = (unsigned short*)alloc((size_t)N * ELLW * 2);
    unsigned short* xb  = (unsigned short*)alloc((size_t)N * IN * 2);
    unsigned short* T1b = (unsigned short*)alloc((size_t)N * IN * 2);
    unsigned short* T2b = (unsigned short*)alloc((size_t)N * IN * 2);
    unsigned short* A2b = (unsigned short*)alloc((size_t)N * IN * 2);
    unsigned short* Ib  = (unsigned short*)alloc((size_t)N * IN * 2);
    unsigned short* hb  = (unsigned short*)alloc((size_t)N * HID * 2);
    unsigned short* Db  = (unsigned short*)alloc((size_t)N * IN * 2);
    unsigned short* Zb  = (unsigned short*)alloc((size_t)N * IN * 2);
    unsigned short* Bt1 = (unsigned short*)alloc((size_t)256 * 384 * 2);
    unsigned short* Bt2 = (unsigned short*)alloc((size_t)384 * 256 * 2);

    dim3 gLap((N + 7) / 8, 2);     // x: 8 nodes/block, y: channel half
    int gBlkM = (N + 127) / 128;
    int nx4 = N * IN / 4;
    int prepItems = 256 * 384 + 384 * 256 + nx4;

    // ---- adjacency + prep ----
    hipMemsetAsync(ibuf, 0, (size_t)2 * N * 4, stream);
    build_kernel<<<(E + 255) / 256, 256, 0, stream>>>(src, dst, degi, cnt, ell, E);
    prep_kernel<<<(prepItems + 255) / 256, 256, 0, stream>>>(W1, W2, x, Bt1, Bt2, xb, nx4);

    // ---- layer 1 ----
    lap_ell_kernel<<<gLap, 256, 0, stream>>>(xb, nullptr, T1b, cnt, ell, degi,
                                             nullptr, nullptr, 1.0f, 0.0f, N);   // T1
    lap_ell_kernel<<<gLap, 256, 0, stream>>>(T1b, nullptr, T2b, cnt, ell, degi,
                                             xb, nullptr, 2.0f, -1.0f, N);       // T2 = 2 L T1 - x
    {
        dim3 grid(gBlkM, 4);   // Ncols = 256
        gemm_mfma_kernel<<<grid, 512, 0, stream>>>(xb, T1b, T2b, IN,
                                                   Bt1, 384,
                                                   hb, hb + 128, nullptr,
                                                   HID, b1, N, 1);
    }

    // ---- layer 2 ----
    {
        dim3 grid(gBlkM, 6);   // Ncols = 384: Db | A2b | Zb
        gemm_mfma_kernel<<<grid, 512, 0, stream>>>(hb, hb + 128, nullptr, HID,
                                                   Bt2, 256,
                                                   Db, A2b, Zb,
                                                   IN, nullptr, N, 0);
        lap_ell_kernel<<<gLap, 256, 0, stream>>>(A2b, nullptr, Ib, cnt, ell, degi,
                                                 Db, nullptr, 2.0f, 1.0f, N);    // I = 2 L A2 + D
        lap_ell_kernel<<<gLap, 256, 0, stream>>>(Ib, out, nullptr, cnt, ell, degi,
                                                 Zb, b2, 1.0f, 1.0f, N);         // out = L I + Z + b2
    }
}

// Round 12
// 204.447 us; speedup vs baseline: 1.1215x; 1.1215x over previous
//
#include <hip/hip_runtime.h>
#include <hip/hip_bf16.h>

// ---------------------------------------------------------------------------
// ChebConv encoder: 2x ChebConv(K=3), sym norm, lambda_max=2 => L_hat = -D^-1/2 A D^-1/2
// N=30000, IN=128, HID=256, E=480000
//
// Round 12 = round 9 (best measured, 209.5us) + two safe deltas:
//  (a) build and prep fused into ONE kernel (independent work; prep's BW work
//      hides under build's atomic stalls; one less launch),
//  (b) ELL indices ushort (halves ELL traffic + build store bytes) with the
//      round-9 exact-tail unroll x4 loop (NOT round-10's padded x8).
// Rounds 10/11 lap rewrites both regressed -> lap structure reverted to r9.
//   layer1: T1b = L xb ; T2b = 2 L T1b - xb ; hb = relu([xb|T1b|T2b]@W1cat + b1)
//   layer2: [Db|A2b|Zb] = hb @ [W1'|W2'|W0'-W2'] ; Ib = 2 L A2b + Db ;
//           out = L Ib + Zb + b2
// ---------------------------------------------------------------------------

#define ELLW 64

typedef short bf16x8_t __attribute__((ext_vector_type(8)));
typedef unsigned short u16x4_t __attribute__((ext_vector_type(4)));
typedef unsigned short u16x8_t __attribute__((ext_vector_type(8)));
typedef float f32x4_t __attribute__((ext_vector_type(4)));

static __device__ inline unsigned short f2bf(float f) {
    __hip_bfloat16 h = __float2bfloat16(f);
    return __builtin_bit_cast(unsigned short, h);
}
static __device__ inline float bfbits2f(unsigned int lo16) {
    unsigned int u = lo16 << 16;
    return __builtin_bit_cast(float, u);
}

// ---------------- fused build || prep ----------------
// blocks [0, gB):        ELL build: degi[s]++ (masked), ell[d*64+cnt[d]++]=s
// blocks [gB, gB+gP):    prep: Bt1 | Bt2 | x->bf16
__global__ __launch_bounds__(256) void build_prep_kernel(
        const int* __restrict__ src, const int* __restrict__ dst,
        int* __restrict__ degi, int* __restrict__ cnt,
        unsigned short* __restrict__ ell, int E, int gB,
        const float* __restrict__ W1, const float* __restrict__ W2,
        const float* __restrict__ x,
        unsigned short* __restrict__ Bt1, unsigned short* __restrict__ Bt2,
        unsigned short* __restrict__ xb, int nx4) {
    int bid = blockIdx.x;
    if (bid < gB) {
        int e = bid * 256 + threadIdx.x;
        if (e >= E) return;
        int s = src[e], d = dst[e];
        if (s != d) atomicAdd(&degi[s], 1);
        int pos = atomicAdd(&cnt[d], 1);
        if (pos < ELLW) ell[(size_t)d * ELLW + pos] = (unsigned short)s;
        return;
    }
    const int NB1 = 256 * 384, NB2 = 384 * 256;
    int i = (bid - gB) * 256 + threadIdx.x;
    if (i < NB1) {
        int n = i / 384, k = i % 384;
        Bt1[(size_t)n * 384 + k] = f2bf(W1[(size_t)k * 256 + n]);
    } else if (i < NB1 + NB2) {
        int j = i - NB1;
        int n = j / 256, k = j % 256;
        float v;
        if (n < 128) v = W2[(size_t)(1 * 256 + k) * 128 + n];
        else if (n < 256) v = W2[(size_t)(2 * 256 + k) * 128 + (n - 128)];
        else v = W2[(size_t)k * 128 + (n - 256)] - W2[(size_t)(2 * 256 + k) * 128 + (n - 256)];
        Bt2[(size_t)n * 256 + k] = f2bf(v);
    } else {
        int j = i - NB1 - NB2;
        if (j < nx4) {
            f32x4_t v = *(const f32x4_t*)&x[(size_t)j * 4];
            u16x4_t u;
            u.x = f2bf(v.x); u.y = f2bf(v.y); u.z = f2bf(v.z); u.w = f2bf(v.w);
            *(u16x4_t*)&xb[(size_t)j * 4] = u;
        }
    }
}

// ---------------- ELL lap, bf16 gather, F=128, unroll x4, exact tail --------
// res = s * sum_e w_e * Xb[ell_e,:] + a*add[node,:] + bias
// w_e = -rsqrt(deg[node]*deg[src_e]), 0 on self-loop/zero-degree.
// One wave per node (64 lanes x 2 channels); round-9 structure, ushort ELL.
__global__ __launch_bounds__(256) void lap_ell_kernel(const unsigned short* __restrict__ Xb,
                                                      float* __restrict__ Yf,
                                                      unsigned short* __restrict__ Yb,
                                                      const int* __restrict__ cnt,
                                                      const unsigned short* __restrict__ ell,
                                                      const int* __restrict__ degi,
                                                      const unsigned short* __restrict__ add,
                                                      const float* __restrict__ bias,
                                                      float s, float a, int N) {
    int wave = threadIdx.x >> 6;
    int lane = threadIdx.x & 63;
    int node = blockIdx.x * 4 + wave;
    if (node >= N) return;
    int n = cnt[node];
    if (n > ELLW) n = ELLW;
    int dn = degi[node];
    float fdn = (float)dn;
    const unsigned short* row = ell + (size_t)node * ELLW;

    float ax0 = 0.f, ay0 = 0.f, ax1 = 0.f, ay1 = 0.f;
    float ax2 = 0.f, ay2 = 0.f, ax3 = 0.f, ay3 = 0.f;
    int j = 0;
    for (; j + 4 <= n; j += 4) {
        u16x4_t s4 = *(const u16x4_t*)&row[j];
        int s0 = __builtin_amdgcn_readfirstlane((int)s4.x);
        int s1 = __builtin_amdgcn_readfirstlane((int)s4.y);
        int s2 = __builtin_amdgcn_readfirstlane((int)s4.z);
        int s3 = __builtin_amdgcn_readfirstlane((int)s4.w);
        unsigned int v0 = *(const unsigned int*)&Xb[(size_t)s0 * 128 + lane * 2];
        unsigned int v1 = *(const unsigned int*)&Xb[(size_t)s1 * 128 + lane * 2];
        unsigned int v2 = *(const unsigned int*)&Xb[(size_t)s2 * 128 + lane * 2];
        unsigned int v3 = *(const unsigned int*)&Xb[(size_t)s3 * 128 + lane * 2];
        int d0 = degi[s0], d1 = degi[s1], d2 = degi[s2], d3 = degi[s3];
        float w0 = (s0 != node && dn > 0 && d0 > 0) ? -rsqrtf(fdn * (float)d0) : 0.0f;
        float w1 = (s1 != node && dn > 0 && d1 > 0) ? -rsqrtf(fdn * (float)d1) : 0.0f;
        float w2 = (s2 != node && dn > 0 && d2 > 0) ? -rsqrtf(fdn * (float)d2) : 0.0f;
        float w3 = (s3 != node && dn > 0 && d3 > 0) ? -rsqrtf(fdn * (float)d3) : 0.0f;
        ax0 = fmaf(w0, bfbits2f(v0 & 0xffffu), ax0);
        ay0 = fmaf(w0, bfbits2f(v0 >> 16), ay0);
        ax1 = fmaf(w1, bfbits2f(v1 & 0xffffu), ax1);
        ay1 = fmaf(w1, bfbits2f(v1 >> 16), ay1);
        ax2 = fmaf(w2, bfbits2f(v2 & 0xffffu), ax2);
        ay2 = fmaf(w2, bfbits2f(v2 >> 16), ay2);
        ax3 = fmaf(w3, bfbits2f(v3 & 0xffffu), ax3);
        ay3 = fmaf(w3, bfbits2f(v3 >> 16), ay3);
    }
    for (; j < n; ++j) {
        int s0 = __builtin_amdgcn_readfirstlane((int)row[j]);
        unsigned int v0 = *(const unsigned int*)&Xb[(size_t)s0 * 128 + lane * 2];
        int d0 = degi[s0];
        float w0 = (s0 != node && dn > 0 && d0 > 0) ? -rsqrtf(fdn * (float)d0) : 0.0f;
        ax0 = fmaf(w0, bfbits2f(v0 & 0xffffu), ax0);
        ay0 = fmaf(w0, bfbits2f(v0 >> 16), ay0);
    }
    float rx = s * ((ax0 + ax1) + (ax2 + ax3));
    float ry = s * ((ay0 + ay1) + (ay2 + ay3));
    size_t o = (size_t)node * 128 + lane * 2;
    if (add) {
        unsigned int ad = *(const unsigned int*)&add[o];
        rx = fmaf(a, bfbits2f(ad & 0xffffu), rx);
        ry = fmaf(a, bfbits2f(ad >> 16), ry);
    }
    if (bias) {
        rx += bias[lane * 2];
        ry += bias[lane * 2 + 1];
    }
    if (Yf) {
        float2 r; r.x = rx; r.y = ry;
        *(float2*)&Yf[o] = r;
    }
    if (Yb) {
        unsigned int ob = ((unsigned int)f2bf(ry) << 16) | f2bf(rx);
        *(unsigned int*)&Yb[o] = ob;
    }
}

// ---------------- bf16 MFMA GEMM, tile 128x64, 512 threads (8 waves) --------
// C[M x Ncols] = Acat[M x K](bf16 segments of 128 cols) @ Bt^T (Bt [Ncols][K] bf16)
// Output: bf16 segments of 128 cols (Ob0/Ob1/Ob2).
__global__ __launch_bounds__(512) void gemm_mfma_kernel(
        const unsigned short* __restrict__ A0, const unsigned short* __restrict__ A1,
        const unsigned short* __restrict__ A2, int ldA,
        const unsigned short* __restrict__ Bt, int K,
        unsigned short* __restrict__ Ob0, unsigned short* __restrict__ Ob1,
        unsigned short* __restrict__ Ob2,
        int ldO, const float* __restrict__ bias, int M, int relu) {
    __shared__ unsigned short As[128][72];  // [row][k], +8 pad
    __shared__ unsigned short Bs[64][72];   // [n][k]

    int tid = threadIdx.x;
    int lane = tid & 63;
    int wid = tid >> 6;          // 0..7
    int wm = wid >> 1;           // 0..3 -> 32-row band
    int wn = wid & 1;            // 0..1 -> 32-col band
    int lm = lane & 15, lg = lane >> 4;

    int rowBase = blockIdx.x * 128;
    int colBase = blockIdx.y * 64;

    f32x4_t acc[2][2] = {};

    for (int k0 = 0; k0 < K; k0 += 64) {
        int seg = k0 >> 7;
        int acol = k0 & 127;
        const unsigned short* A = (seg == 0) ? A0 : ((seg == 1) ? A1 : A2);

        // stage A: 128 rows x 64 bf16 = 16KB; 512 threads x 32B
        {
            int row = tid >> 2;            // 0..127
            int c = (tid & 3) * 16;        // 0,16,32,48
            int gr = rowBase + row;
            u16x8_t v0 = {0, 0, 0, 0, 0, 0, 0, 0};
            u16x8_t v1 = {0, 0, 0, 0, 0, 0, 0, 0};
            if (gr < M) {
                const unsigned short* ap = &A[(size_t)gr * ldA + acol + c];
                v0 = *(const u16x8_t*)ap;
                v1 = *(const u16x8_t*)(ap + 8);
            }
            *(u16x8_t*)&As[row][c] = v0;
            *(u16x8_t*)&As[row][c + 8] = v1;
        }
        // stage Bt: 64 n-rows x 64 k = 8KB; 512 threads x 16B
        {
            int n = tid >> 3;              // 0..63
            int kb = tid & 7;
            u16x8_t bv = *(const u16x8_t*)&Bt[(size_t)(colBase + n) * K + k0 + kb * 8];
            *(u16x8_t*)&Bs[n][kb * 8] = bv;
        }
        __syncthreads();

#pragma unroll
        for (int ks = 0; ks < 2; ++ks) {
            int koff = ks * 32 + lg * 8;
            bf16x8_t a0 = *(const bf16x8_t*)&As[wm * 32 + lm][koff];
            bf16x8_t a1 = *(const bf16x8_t*)&As[wm * 32 + 16 + lm][koff];
            bf16x8_t b0 = *(const bf16x8_t*)&Bs[wn * 32 + lm][koff];
            bf16x8_t b1 = *(const bf16x8_t*)&Bs[wn * 32 + 16 + lm][koff];
            acc[0][0] = __builtin_amdgcn_mfma_f32_16x16x32_bf16(a0, b0, acc[0][0], 0, 0, 0);
            acc[0][1] = __builtin_amdgcn_mfma_f32_16x16x32_bf16(a0, b1, acc[0][1], 0, 0, 0);
            acc[1][0] = __builtin_amdgcn_mfma_f32_16x16x32_bf16(a1, b0, acc[1][0], 0, 0, 0);
            acc[1][1] = __builtin_amdgcn_mfma_f32_16x16x32_bf16(a1, b1, acc[1][1], 0, 0, 0);
        }
        __syncthreads();
    }

    // epilogue: C/D layout col=lane&15, row=(lane>>4)*4+reg  [m89]
    int oseg = colBase >> 7;
    unsigned short* Ob = (oseg == 0) ? Ob0 : ((oseg == 1) ? Ob1 : Ob2);
    int lcbase = (colBase & 127) + wn * 32;
#pragma unroll
    for (int i = 0; i < 2; ++i) {
#pragma unroll
        for (int j = 0; j < 2; ++j) {
            int lc = lcbase + j * 16 + lm;
            int gcol = colBase + wn * 32 + j * 16 + lm;
            float bval = bias ? bias[gcol] : 0.0f;
#pragma unroll
            for (int r = 0; r < 4; ++r) {
                int gr = rowBase + wm * 32 + i * 16 + lg * 4 + r;
                if (gr < M) {
                    float v = acc[i][j][r] + bval;
                    if (relu) v = fmaxf(v, 0.0f);
                    Ob[(size_t)gr * ldO + lc] = f2bf(v);
                }
            }
        }
    }
}

extern "C" void kernel_launch(void* const* d_in, const int* in_sizes, int n_in,
                              void* d_out, int out_size, void* d_ws, size_t ws_size,
                              hipStream_t stream) {
    const float* x  = (const float*)d_in[0];
    const int*   ei = (const int*)d_in[1];
    const float* W1 = (const float*)d_in[2];
    const float* b1 = (const float*)d_in[3];
    const float* W2 = (const float*)d_in[4];
    const float* b2 = (const float*)d_in[5];
    float* out = (float*)d_out;

    const int IN = 128, HID = 256;
    int N = in_sizes[0] / IN;   // 30000
    int E = in_sizes[1] / 2;    // 480000
    const int* src = ei;
    const int* dst = ei + E;

    char* ws = (char*)d_ws;
    size_t off = 0;
    auto alloc = [&](size_t bytes) -> void* {
        void* p = ws + off;
        off += (bytes + 255) & ~(size_t)255;
        return p;
    };
    int* ibuf   = (int*)alloc((size_t)2 * N * 4);   // degi|cnt, one memset
    int* degi   = ibuf;
    int* cnt    = ibuf + N;
    unsigned short* ell = (unsigned short*)alloc((size_t)N * ELLW * 2);
    unsigned short* xb  = (unsigned short*)alloc((size_t)N * IN * 2);
    unsigned short* T1b = (unsigned short*)alloc((size_t)N * IN * 2);
    unsigned short* T2b = (unsigned short*)alloc((size_t)N * IN * 2);
    unsigned short* A2b = (unsigned short*)alloc((size_t)N * IN * 2);
    unsigned short* Ib  = (unsigned short*)alloc((size_t)N * IN * 2);
    unsigned short* hb  = (unsigned short*)alloc((size_t)N * HID * 2);
    unsigned short* Db  = (unsigned short*)alloc((size_t)N * IN * 2);
    unsigned short* Zb  = (unsigned short*)alloc((size_t)N * IN * 2);
    unsigned short* Bt1 = (unsigned short*)alloc((size_t)256 * 384 * 2);
    unsigned short* Bt2 = (unsigned short*)alloc((size_t)384 * 256 * 2);

    int gLap = (N + 3) / 4;
    int gBlkM = (N + 127) / 128;
    int nx4 = N * IN / 4;
    int gB = (E + 255) / 256;                              // build blocks
    int gP = (256 * 384 + 384 * 256 + nx4 + 255) / 256;    // prep blocks

    // ---- adjacency + prep (fused, independent halves) ----
    hipMemsetAsync(ibuf, 0, (size_t)2 * N * 4, stream);
    build_prep_kernel<<<gB + gP, 256, 0, stream>>>(src, dst, degi, cnt, ell, E, gB,
                                                   W1, W2, x, Bt1, Bt2, xb, nx4);

    // ---- layer 1 ----
    lap_ell_kernel<<<gLap, 256, 0, stream>>>(xb, nullptr, T1b, cnt, ell, degi,
                                             nullptr, nullptr, 1.0f, 0.0f, N);   // T1
    lap_ell_kernel<<<gLap, 256, 0, stream>>>(T1b, nullptr, T2b, cnt, ell, degi,
                                             xb, nullptr, 2.0f, -1.0f, N);       // T2 = 2 L T1 - x
    {
        dim3 grid(gBlkM, 4);   // Ncols = 256
        gemm_mfma_kernel<<<grid, 512, 0, stream>>>(xb, T1b, T2b, IN,
                                                   Bt1, 384,
                                                   hb, hb + 128, nullptr,
                                                   HID, b1, N, 1);
    }

    // ---- layer 2 ----
    {
        dim3 grid(gBlkM, 6);   // Ncols = 384: Db | A2b | Zb
        gemm_mfma_kernel<<<grid, 512, 0, stream>>>(hb, hb + 128, nullptr, HID,
                                                   Bt2, 256,
                                                   Db, A2b, Zb,
                                                   IN, nullptr, N, 0);
        lap_ell_kernel<<<gLap, 256, 0, stream>>>(A2b, nullptr, Ib, cnt, ell, degi,
                                                 Db, nullptr, 2.0f, 1.0f, N);    // I = 2 L A2 + D
        lap_ell_kernel<<<gLap, 256, 0, stream>>>(Ib, out, nullptr, cnt, ell, degi,
                                                 Zb, b2, 1.0f, 1.0f, N);         // out = L I + Z + b2
    }
}

// Round 13
// 187.177 us; speedup vs baseline: 1.2249x; 1.0923x over previous
//
#include <hip/hip_runtime.h>
#include <hip/hip_bf16.h>

// ---------------------------------------------------------------------------
// ChebConv encoder: 2x ChebConv(K=3), sym norm, lambda_max=2 => L_hat = -D^-1/2 A D^-1/2
// N=30000, IN=128, HID=256, E=480000
//
// Round 13 = round 12 (204.4us) + two deltas:
//  (a) GEMM tile 128x128 @512thr (acc[2][4]/wave, 2x MACs per staged byte,
//      half the blocks),
//  (b) lap exact-tail unroll x8 (u16x8 index load, 8 gathers in flight, NO
//      padding waste - round 10's mistake) + hoisted rsqrt(deg[node]).
// Build/prep fused kernel unchanged (accepted atomic-write floor ~48us).
//   layer1: T1b = L xb ; T2b = 2 L T1b - xb ; hb = relu([xb|T1b|T2b]@W1cat + b1)
//   layer2: [Db|A2b|Zb] = hb @ [W1'|W2'|W0'-W2'] ; Ib = 2 L A2b + Db ;
//           out = L Ib + Zb + b2
// ---------------------------------------------------------------------------

#define ELLW 64

typedef short bf16x8_t __attribute__((ext_vector_type(8)));
typedef unsigned short u16x4_t __attribute__((ext_vector_type(4)));
typedef unsigned short u16x8_t __attribute__((ext_vector_type(8)));
typedef float f32x4_t __attribute__((ext_vector_type(4)));

static __device__ inline unsigned short f2bf(float f) {
    __hip_bfloat16 h = __float2bfloat16(f);
    return __builtin_bit_cast(unsigned short, h);
}
static __device__ inline float bfbits2f(unsigned int lo16) {
    unsigned int u = lo16 << 16;
    return __builtin_bit_cast(float, u);
}

// ---------------- fused build || prep ----------------
// blocks [0, gB):        ELL build: degi[s]++ (masked), ell[d*64+cnt[d]++]=s
// blocks [gB, gB+gP):    prep: Bt1 | Bt2 | x->bf16
__global__ __launch_bounds__(256) void build_prep_kernel(
        const int* __restrict__ src, const int* __restrict__ dst,
        int* __restrict__ degi, int* __restrict__ cnt,
        unsigned short* __restrict__ ell, int E, int gB,
        const float* __restrict__ W1, const float* __restrict__ W2,
        const float* __restrict__ x,
        unsigned short* __restrict__ Bt1, unsigned short* __restrict__ Bt2,
        unsigned short* __restrict__ xb, int nx4) {
    int bid = blockIdx.x;
    if (bid < gB) {
        int e = bid * 256 + threadIdx.x;
        if (e >= E) return;
        int s = src[e], d = dst[e];
        if (s != d) atomicAdd(&degi[s], 1);
        int pos = atomicAdd(&cnt[d], 1);
        if (pos < ELLW) ell[(size_t)d * ELLW + pos] = (unsigned short)s;
        return;
    }
    const int NB1 = 256 * 384, NB2 = 384 * 256;
    int i = (bid - gB) * 256 + threadIdx.x;
    if (i < NB1) {
        int n = i / 384, k = i % 384;
        Bt1[(size_t)n * 384 + k] = f2bf(W1[(size_t)k * 256 + n]);
    } else if (i < NB1 + NB2) {
        int j = i - NB1;
        int n = j / 256, k = j % 256;
        float v;
        if (n < 128) v = W2[(size_t)(1 * 256 + k) * 128 + n];
        else if (n < 256) v = W2[(size_t)(2 * 256 + k) * 128 + (n - 128)];
        else v = W2[(size_t)k * 128 + (n - 256)] - W2[(size_t)(2 * 256 + k) * 128 + (n - 256)];
        Bt2[(size_t)n * 256 + k] = f2bf(v);
    } else {
        int j = i - NB1 - NB2;
        if (j < nx4) {
            f32x4_t v = *(const f32x4_t*)&x[(size_t)j * 4];
            u16x4_t u;
            u.x = f2bf(v.x); u.y = f2bf(v.y); u.z = f2bf(v.z); u.w = f2bf(v.w);
            *(u16x4_t*)&xb[(size_t)j * 4] = u;
        }
    }
}

// ---------------- ELL lap, bf16 gather, F=128, unroll x8/x4/x1 exact --------
// res = s * sum_e w_e * Xb[ell_e,:] + a*add[node,:] + bias
// w_e = -rsqrt(deg[node])*rsqrt(deg[src_e]), 0 on self-loop/zero-degree.
// One wave per node (64 lanes x 2 channels).
__global__ __launch_bounds__(256) void lap_ell_kernel(const unsigned short* __restrict__ Xb,
                                                      float* __restrict__ Yf,
                                                      unsigned short* __restrict__ Yb,
                                                      const int* __restrict__ cnt,
                                                      const unsigned short* __restrict__ ell,
                                                      const int* __restrict__ degi,
                                                      const unsigned short* __restrict__ add,
                                                      const float* __restrict__ bias,
                                                      float s, float a, int N) {
    int wave = threadIdx.x >> 6;
    int lane = threadIdx.x & 63;
    int node = blockIdx.x * 4 + wave;
    if (node >= N) return;
    int n = cnt[node];
    if (n > ELLW) n = ELLW;
    int dn = degi[node];
    float rn = (dn > 0) ? rsqrtf((float)dn) : 0.0f;
    const unsigned short* row = ell + (size_t)node * ELLW;

    float ax[8], ay[8];
#pragma unroll
    for (int k = 0; k < 8; ++k) { ax[k] = 0.0f; ay[k] = 0.0f; }

    int j = 0;
    for (; j + 8 <= n; j += 8) {
        u16x8_t s8 = *(const u16x8_t*)&row[j];
#pragma unroll
        for (int k = 0; k < 8; ++k) {
            int sk = __builtin_amdgcn_readfirstlane((int)s8[k]);
            unsigned int v = *(const unsigned int*)&Xb[(size_t)sk * 128 + lane * 2];
            int dsk = degi[sk];
            float wk = (sk != node && dsk > 0) ? -rn * rsqrtf((float)dsk) : 0.0f;
            ax[k] = fmaf(wk, bfbits2f(v & 0xffffu), ax[k]);
            ay[k] = fmaf(wk, bfbits2f(v >> 16), ay[k]);
        }
    }
    if (j + 4 <= n) {
        u16x4_t s4 = *(const u16x4_t*)&row[j];
#pragma unroll
        for (int k = 0; k < 4; ++k) {
            int sk = __builtin_amdgcn_readfirstlane((int)s4[k]);
            unsigned int v = *(const unsigned int*)&Xb[(size_t)sk * 128 + lane * 2];
            int dsk = degi[sk];
            float wk = (sk != node && dsk > 0) ? -rn * rsqrtf((float)dsk) : 0.0f;
            ax[k] = fmaf(wk, bfbits2f(v & 0xffffu), ax[k]);
            ay[k] = fmaf(wk, bfbits2f(v >> 16), ay[k]);
        }
        j += 4;
    }
    for (; j < n; ++j) {
        int sk = __builtin_amdgcn_readfirstlane((int)row[j]);
        unsigned int v = *(const unsigned int*)&Xb[(size_t)sk * 128 + lane * 2];
        int dsk = degi[sk];
        float wk = (sk != node && dsk > 0) ? -rn * rsqrtf((float)dsk) : 0.0f;
        ax[0] = fmaf(wk, bfbits2f(v & 0xffffu), ax[0]);
        ay[0] = fmaf(wk, bfbits2f(v >> 16), ay[0]);
    }
    float rx = s * (((ax[0] + ax[1]) + (ax[2] + ax[3])) +
                    ((ax[4] + ax[5]) + (ax[6] + ax[7])));
    float ry = s * (((ay[0] + ay[1]) + (ay[2] + ay[3])) +
                    ((ay[4] + ay[5]) + (ay[6] + ay[7])));
    size_t o = (size_t)node * 128 + lane * 2;
    if (add) {
        unsigned int ad = *(const unsigned int*)&add[o];
        rx = fmaf(a, bfbits2f(ad & 0xffffu), rx);
        ry = fmaf(a, bfbits2f(ad >> 16), ry);
    }
    if (bias) {
        rx += bias[lane * 2];
        ry += bias[lane * 2 + 1];
    }
    if (Yf) {
        float2 r; r.x = rx; r.y = ry;
        *(float2*)&Yf[o] = r;
    }
    if (Yb) {
        unsigned int ob = ((unsigned int)f2bf(ry) << 16) | f2bf(rx);
        *(unsigned int*)&Yb[o] = ob;
    }
}

// ---------------- bf16 MFMA GEMM, tile 128x128, 512 threads (8 waves) -------
// C[M x Ncols] = Acat[M x K](bf16 segments of 128 cols) @ Bt^T (Bt [Ncols][K] bf16)
// Output: bf16 segments of 128 cols (Ob0/Ob1/Ob2); blockIdx.y = segment.
// 8 waves as 4x2: each wave 32 rows x 64 cols = acc[2][4] of 16x16 frags.
__global__ __launch_bounds__(512) void gemm_mfma_kernel(
        const unsigned short* __restrict__ A0, const unsigned short* __restrict__ A1,
        const unsigned short* __restrict__ A2, int ldA,
        const unsigned short* __restrict__ Bt, int K,
        unsigned short* __restrict__ Ob0, unsigned short* __restrict__ Ob1,
        unsigned short* __restrict__ Ob2,
        int ldO, const float* __restrict__ bias, int M, int relu) {
    __shared__ unsigned short As[128][72];  // [row][k], +8 pad
    __shared__ unsigned short Bs[128][72];  // [n][k]

    int tid = threadIdx.x;
    int lane = tid & 63;
    int wid = tid >> 6;          // 0..7
    int wm = wid >> 1;           // 0..3 -> 32-row band
    int wn = wid & 1;            // 0..1 -> 64-col band
    int lm = lane & 15, lg = lane >> 4;

    int rowBase = blockIdx.x * 128;
    int colBase = blockIdx.y * 128;

    f32x4_t acc[2][4] = {};

    for (int k0 = 0; k0 < K; k0 += 64) {
        int seg = k0 >> 7;
        int acol = k0 & 127;
        const unsigned short* A = (seg == 0) ? A0 : ((seg == 1) ? A1 : A2);

        // stage A: 128 rows x 64 bf16 = 16KB; 512 threads x 32B
        {
            int row = tid >> 2;            // 0..127
            int c = (tid & 3) * 16;        // 0,16,32,48
            int gr = rowBase + row;
            u16x8_t v0 = {0, 0, 0, 0, 0, 0, 0, 0};
            u16x8_t v1 = {0, 0, 0, 0, 0, 0, 0, 0};
            if (gr < M) {
                const unsigned short* ap = &A[(size_t)gr * ldA + acol + c];
                v0 = *(const u16x8_t*)ap;
                v1 = *(const u16x8_t*)(ap + 8);
            }
            *(u16x8_t*)&As[row][c] = v0;
            *(u16x8_t*)&As[row][c + 8] = v1;
        }
        // stage Bt: 128 n-rows x 64 k = 16KB; 512 threads x 32B
        {
            int n = tid >> 2;              // 0..127
            int kb = (tid & 3) * 16;       // 0,16,32,48
            const unsigned short* bp = &Bt[(size_t)(colBase + n) * K + k0 + kb];
            u16x8_t b0 = *(const u16x8_t*)bp;
            u16x8_t b1 = *(const u16x8_t*)(bp + 8);
            *(u16x8_t*)&Bs[n][kb] = b0;
            *(u16x8_t*)&Bs[n][kb + 8] = b1;
        }
        __syncthreads();

#pragma unroll
        for (int ks = 0; ks < 2; ++ks) {
            int koff = ks * 32 + lg * 8;
            bf16x8_t a0 = *(const bf16x8_t*)&As[wm * 32 + lm][koff];
            bf16x8_t a1 = *(const bf16x8_t*)&As[wm * 32 + 16 + lm][koff];
            bf16x8_t b0 = *(const bf16x8_t*)&Bs[wn * 64 + lm][koff];
            bf16x8_t b1 = *(const bf16x8_t*)&Bs[wn * 64 + 16 + lm][koff];
            bf16x8_t b2 = *(const bf16x8_t*)&Bs[wn * 64 + 32 + lm][koff];
            bf16x8_t b3 = *(const bf16x8_t*)&Bs[wn * 64 + 48 + lm][koff];
            acc[0][0] = __builtin_amdgcn_mfma_f32_16x16x32_bf16(a0, b0, acc[0][0], 0, 0, 0);
            acc[0][1] = __builtin_amdgcn_mfma_f32_16x16x32_bf16(a0, b1, acc[0][1], 0, 0, 0);
            acc[0][2] = __builtin_amdgcn_mfma_f32_16x16x32_bf16(a0, b2, acc[0][2], 0, 0, 0);
            acc[0][3] = __builtin_amdgcn_mfma_f32_16x16x32_bf16(a0, b3, acc[0][3], 0, 0, 0);
            acc[1][0] = __builtin_amdgcn_mfma_f32_16x16x32_bf16(a1, b0, acc[1][0], 0, 0, 0);
            acc[1][1] = __builtin_amdgcn_mfma_f32_16x16x32_bf16(a1, b1, acc[1][1], 0, 0, 0);
            acc[1][2] = __builtin_amdgcn_mfma_f32_16x16x32_bf16(a1, b2, acc[1][2], 0, 0, 0);
            acc[1][3] = __builtin_amdgcn_mfma_f32_16x16x32_bf16(a1, b3, acc[1][3], 0, 0, 0);
        }
        __syncthreads();
    }

    // epilogue: C/D layout col=lane&15, row=(lane>>4)*4+reg  [m89]
    int oseg = blockIdx.y;
    unsigned short* Ob = (oseg == 0) ? Ob0 : ((oseg == 1) ? Ob1 : Ob2);
#pragma unroll
    for (int i = 0; i < 2; ++i) {
#pragma unroll
        for (int j = 0; j < 4; ++j) {
            int lc = wn * 64 + j * 16 + lm;        // col within 128-seg
            int gcol = colBase + lc;               // global col (bias)
            float bval = bias ? bias[gcol] : 0.0f;
#pragma unroll
            for (int r = 0; r < 4; ++r) {
                int gr = rowBase + wm * 32 + i * 16 + lg * 4 + r;
                if (gr < M) {
                    float v = acc[i][j][r] + bval;
                    if (relu) v = fmaxf(v, 0.0f);
                    Ob[(size_t)gr * ldO + lc] = f2bf(v);
                }
            }
        }
    }
}

extern "C" void kernel_launch(void* const* d_in, const int* in_sizes, int n_in,
                              void* d_out, int out_size, void* d_ws, size_t ws_size,
                              hipStream_t stream) {
    const float* x  = (const float*)d_in[0];
    const int*   ei = (const int*)d_in[1];
    const float* W1 = (const float*)d_in[2];
    const float* b1 = (const float*)d_in[3];
    const float* W2 = (const float*)d_in[4];
    const float* b2 = (const float*)d_in[5];
    float* out = (float*)d_out;

    const int IN = 128, HID = 256;
    int N = in_sizes[0] / IN;   // 30000
    int E = in_sizes[1] / 2;    // 480000
    const int* src = ei;
    const int* dst = ei + E;

    char* ws = (char*)d_ws;
    size_t off = 0;
    auto alloc = [&](size_t bytes) -> void* {
        void* p = ws + off;
        off += (bytes + 255) & ~(size_t)255;
        return p;
    };
    int* ibuf   = (int*)alloc((size_t)2 * N * 4);   // degi|cnt, one memset
    int* degi   = ibuf;
    int* cnt    = ibuf + N;
    unsigned short* ell = (unsigned short*)alloc((size_t)N * ELLW * 2);
    unsigned short* xb  = (unsigned short*)alloc((size_t)N * IN * 2);
    unsigned short* T1b = (unsigned short*)alloc((size_t)N * IN * 2);
    unsigned short* T2b = (unsigned short*)alloc((size_t)N * IN * 2);
    unsigned short* A2b = (unsigned short*)alloc((size_t)N * IN * 2);
    unsigned short* Ib  = (unsigned short*)alloc((size_t)N * IN * 2);
    unsigned short* hb  = (unsigned short*)alloc((size_t)N * HID * 2);
    unsigned short* Db  = (unsigned short*)alloc((size_t)N * IN * 2);
    unsigned short* Zb  = (unsigned short*)alloc((size_t)N * IN * 2);
    unsigned short* Bt1 = (unsigned short*)alloc((size_t)256 * 384 * 2);
    unsigned short* Bt2 = (unsigned short*)alloc((size_t)384 * 256 * 2);

    int gLap = (N + 3) / 4;
    int gBlkM = (N + 127) / 128;
    int nx4 = N * IN / 4;
    int gB = (E + 255) / 256;                              // build blocks
    int gP = (256 * 384 + 384 * 256 + nx4 + 255) / 256;    // prep blocks

    // ---- adjacency + prep (fused, independent halves) ----
    hipMemsetAsync(ibuf, 0, (size_t)2 * N * 4, stream);
    build_prep_kernel<<<gB + gP, 256, 0, stream>>>(src, dst, degi, cnt, ell, E, gB,
                                                   W1, W2, x, Bt1, Bt2, xb, nx4);

    // ---- layer 1 ----
    lap_ell_kernel<<<gLap, 256, 0, stream>>>(xb, nullptr, T1b, cnt, ell, degi,
                                             nullptr, nullptr, 1.0f, 0.0f, N);   // T1
    lap_ell_kernel<<<gLap, 256, 0, stream>>>(T1b, nullptr, T2b, cnt, ell, degi,
                                             xb, nullptr, 2.0f, -1.0f, N);       // T2 = 2 L T1 - x
    {
        dim3 grid(gBlkM, 2);   // Ncols = 256, two 128-col segments
        gemm_mfma_kernel<<<grid, 512, 0, stream>>>(xb, T1b, T2b, IN,
                                                   Bt1, 384,
                                                   hb, hb + 128, nullptr,
                                                   HID, b1, N, 1);
    }

    // ---- layer 2 ----
    {
        dim3 grid(gBlkM, 3);   // Ncols = 384: Db | A2b | Zb
        gemm_mfma_kernel<<<grid, 512, 0, stream>>>(hb, hb + 128, nullptr, HID,
                                                   Bt2, 256,
                                                   Db, A2b, Zb,
                                                   IN, nullptr, N, 0);
        lap_ell_kernel<<<gLap, 256, 0, stream>>>(A2b, nullptr, Ib, cnt, ell, degi,
                                                 Db, nullptr, 2.0f, 1.0f, N);    // I = 2 L A2 + D
        lap_ell_kernel<<<gLap, 256, 0, stream>>>(Ib, out, nullptr, cnt, ell, degi,
                                                 Zb, b2, 1.0f, 1.0f, N);         // out = L I + Z + b2
    }
}